// Round 16
// baseline (497.556 us; speedup 1.0000x reference)
//
#include <hip/hip_runtime.h>
#include <hip/hip_bf16.h>

#define NN 10000
#define EE 120000
#define E_PAD 120064   // 1876 * 64
#define NT64 1876      // E_PAD / 64

#define H1S 136        // h1 LDS row stride (elems); 68 words ≡ 4 (mod 32)
#define H2S 264        // h2 LDS row stride (elems); 132 words ≡ 4 (mod 32)

typedef __bf16 bf16_t;
typedef __bf16 bf16x8 __attribute__((ext_vector_type(8)));
typedef float f32x4 __attribute__((ext_vector_type(4)));

#define DOT16(A0, A1, A2, A3, W0, W1)                                          \
    (A0.x * (float)W0[0] + A0.y * (float)W0[1] + A0.z * (float)W0[2] +         \
     A0.w * (float)W0[3] + A1.x * (float)W0[4] + A1.y * (float)W0[5] +         \
     A1.z * (float)W0[6] + A1.w * (float)W0[7] + A2.x * (float)W1[0] +         \
     A2.y * (float)W1[1] + A2.z * (float)W1[2] + A2.w * (float)W1[3] +         \
     A3.x * (float)W1[4] + A3.y * (float)W1[5] + A3.z * (float)W1[6] +         \
     A3.w * (float)W1[7])

static __device__ __forceinline__ int clampi(int v) {
    return v < 0 ? 0 : (v >= NN ? NN - 1 : v);
}

// read element i of a raw input tensor per detected dtype, sanitized
static __device__ __forceinline__ float ldf(const void* p, int i, int f) {
    float v = f ? ((const float*)p)[i] : (float)((const bf16_t*)p)[i];
    return isfinite(v) ? v : 0.f;
}

// ---- combined dtype detection (float + index) ------------------------------
__global__ __launch_bounds__(256) void detect_all(const unsigned short* __restrict__ ea_raw,
                                                  const int* __restrict__ ei,
                                                  int* __restrict__ f32fl,
                                                  int* __restrict__ idxfl) {
    int t = blockIdx.x * 256 + threadIdx.x;          // [0, 8192)
    if (ea_raw[t] & 0x8000) atomicOr(f32fl, 1);
    if (t < 4096 && ei[2 * t + 1] != 0) atomicOr(idxfl, 1);
}

// ---- batched convert of all 16 float tensors + fused misc prep -------------
#define N_FLT 16
#define MISC_TOT 615936
struct CvtArgs {
    const void* src[N_FLT];
    float* dst;
    int offs[N_FLT];
    int n[N_FLT];
    int tot;
};

// segments past a.tot: k2 transpose | k3 transpose+permute | k3 bias | h0
__global__ __launch_bounds__(256) void cvt_misc(CvtArgs a, const int* __restrict__ isf32,
                                                bf16_t* __restrict__ k2t,
                                                bf16_t* __restrict__ k3t,
                                                float* __restrict__ k3bp,
                                                float* __restrict__ h0) {
    int i = blockIdx.x * 256 + threadIdx.x;
    int f = *isf32;
    if (i < a.tot) {
        int t = 0;
#pragma unroll
        for (int k = 1; k < N_FLT; ++k) if (i >= a.offs[k]) t = k;
        int il = i - a.offs[t];
        float v;
        if (f) v = ((const float*)a.src[t])[il];
        else   v = (float)((const bf16_t*)a.src[t])[il];
        if (!isfinite(v)) v = 0.f;
        a.dst[i] = v;
        return;
    }
    int j = i - a.tot;
    if (j >= MISC_TOT) return;
    const void* k2w  = a.src[6];
    const void* k3w  = a.src[8];
    const void* k3b  = a.src[9];
    const void* x    = a.src[0];
    const void* fc1w = a.src[2];
    const void* fc1b = a.src[3];
    if (j < 32768) {                       // k2t[n*128+k] = k2w[k*256+n]
        int n = j >> 7, k = j & 127;
        k2t[j] = (bf16_t)ldf(k2w, k * 256 + n, f);
    } else if (j < 294912) {               // k3t[n*256+k] = k3w[k*1024+perm(n)]
        int idx = j - 32768;
        int n = idx >> 8, k = idx & 255;
        int c = ((n & 31) << 5) | (n >> 5);
        k3t[idx] = (bf16_t)ldf(k3w, k * 1024 + c, f);
    } else if (j < 295936) {               // k3bp
        int n = j - 294912;
        k3bp[n] = ldf(k3b, ((n & 31) << 5) | (n >> 5), f);
    } else {                               // h0 = x @ fc1_w + fc1_b
        int gid = j - 295936;
        int n = gid >> 5, o = gid & 31;
        float acc = ldf(fc1b, o, f);
#pragma unroll
        for (int jj = 0; jj < 6; ++jj) acc += ldf(x, n * 6 + jj, f) * ldf(fc1w, jj * 32 + o, f);
        h0[gid] = acc;
    }
}

__global__ __launch_bounds__(256) void repack_idx(const int* __restrict__ ei,
                                                  const int* __restrict__ flag,
                                                  int* __restrict__ s,
                                                  int* __restrict__ d,
                                                  int* __restrict__ cnti) {
    int e = blockIdx.x * 256 + threadIdx.x;
    if (e >= EE) return;
    int sv, dv;
    if (*flag == 0) {   // int64
        sv = clampi(ei[2 * e]);
        dv = clampi(ei[2 * (EE + e)]);
    } else {            // int32
        sv = clampi(ei[e]);
        dv = clampi(ei[EE + e]);
    }
    s[e] = sv;
    d[e] = dv;
    atomicAdd(&cnti[dv], 1);
}

// single-block exclusive scan of cnti[NN] -> row_off[NN+1], pos copy
__global__ __launch_bounds__(256) void scan_kernel(const int* __restrict__ cnti,
                                                   int* __restrict__ row_off,
                                                   int* __restrict__ pos) {
    __shared__ int part[256];
    const int t = threadIdx.x;
    const int CH = (NN + 255) / 256;
    int s = 0;
    for (int i = 0; i < CH; ++i) {
        int idx = t * CH + i;
        if (idx < NN) s += cnti[idx];
    }
    part[t] = s;
    __syncthreads();
    for (int off = 1; off < 256; off <<= 1) {
        int tmp = (t >= off) ? part[t - off] : 0;
        __syncthreads();
        part[t] += tmp;
        __syncthreads();
    }
    int run = part[t] - s;
    for (int i = 0; i < CH; ++i) {
        int idx = t * CH + i;
        if (idx < NN) {
            row_off[idx] = run;
            pos[idx] = run;
            run += cnti[idx];
        }
    }
    if (t == 255) row_off[NN] = run;
}

// rank[e] = dst-sorted position of edge e; src_s[p] = src of sorted edge p
__global__ __launch_bounds__(256) void scatter_rank(const int* __restrict__ dst,
                                                    const int* __restrict__ src,
                                                    int* __restrict__ pos,
                                                    int* __restrict__ rank,
                                                    int* __restrict__ src_s) {
    int e = blockIdx.x * 256 + threadIdx.x;
    if (e >= E_PAD) return;
    if (e >= EE) { rank[e] = e; return; }
    int p = atomicAdd(&pos[dst[e]], 1);
    rank[e] = p;
    src_s[p] = src[e];
}

// ---- FUSED PREP v3 (round-11 exact; measured 174 us, FETCH ~8 MB) ----------
__global__ __launch_bounds__(256, 3) void fused_prep(const float* __restrict__ ea,
                                                     const float* __restrict__ k1w,
                                                     const float* __restrict__ k1b,
                                                     const bf16_t* __restrict__ k2t,
                                                     const float* __restrict__ k2b,
                                                     const bf16_t* __restrict__ k3t,
                                                     const float* __restrict__ k3bp,
                                                     bf16_t* __restrict__ we,
                                                     const int* __restrict__ rank,
                                                     int tile0, int perm) {
    __shared__ bf16_t h1_s[64 * H1S];   // 17408 B
    __shared__ bf16_t h2_s[64 * H2S];   // 33792 B
    float* ea_s  = (float*)h2_s;
    float* k1w_s = ea_s + 384;
    float* k1b_s = k1w_s + 768;

    const int t = threadIdx.x;
    const int e0 = (tile0 + blockIdx.x) * 64;

    for (int i = t; i < 384; i += 256) {
        int r = i / 6, j = i - r * 6;
        int e = e0 + r;
        ea_s[i] = (e < EE) ? ea[(size_t)e * 6 + j] : 0.f;
    }
    for (int i = t; i < 768; i += 256) k1w_s[i] = k1w[i];
    if (t < 128) k1b_s[t] = k1b[t];
    __syncthreads();

    {
        const int o = t & 127, rh = t >> 7;
        for (int r = rh * 32; r < rh * 32 + 32; ++r) {
            float acc = k1b_s[o];
#pragma unroll
            for (int j = 0; j < 6; ++j) acc += ea_s[r * 6 + j] * k1w_s[j * 128 + o];
            h1_s[r * H1S + o] = (bf16_t)fmaxf(acc, 0.f);
        }
    }
    __syncthreads();

    const int lane = t & 63;
    const int w = t >> 6;
    const int nr16 = lane & 15;
    const int koff = (lane >> 4) * 8;
    const int rbase = (lane >> 4) * 4;

    {
        f32x4 acc[4][4];
#pragma unroll
        for (int i = 0; i < 4; ++i)
#pragma unroll
            for (int j = 0; j < 4; ++j) acc[i][j] = f32x4{0.f, 0.f, 0.f, 0.f};
        bf16x8 bcur[4], bnxt[4];
#pragma unroll
        for (int j = 0; j < 4; ++j)
            bcur[j] = *(const bf16x8*)&k2t[(w * 64 + j * 16 + nr16) * 128 + koff];
#pragma unroll 1
        for (int ks = 0; ks < 4; ++ks) {
            const int k0 = ks * 32;
            if (ks < 3) {
#pragma unroll
                for (int j = 0; j < 4; ++j)
                    bnxt[j] = *(const bf16x8*)&k2t[(w * 64 + j * 16 + nr16) * 128 + k0 + 32 + koff];
            }
            bf16x8 af[4];
#pragma unroll
            for (int i = 0; i < 4; ++i)
                af[i] = *(const bf16x8*)&h1_s[(nr16 + i * 16) * H1S + k0 + koff];
#pragma unroll
            for (int i = 0; i < 4; ++i)
#pragma unroll
                for (int j = 0; j < 4; ++j)
                    acc[i][j] = __builtin_amdgcn_mfma_f32_16x16x32_bf16(af[i], bcur[j], acc[i][j], 0, 0, 0);
#pragma unroll
            for (int j = 0; j < 4; ++j) bcur[j] = bnxt[j];
        }
#pragma unroll
        for (int i = 0; i < 4; ++i) {
#pragma unroll
            for (int j = 0; j < 4; ++j) {
                int col = w * 64 + j * 16 + nr16;
                float bv = k2b[col];
#pragma unroll
                for (int r = 0; r < 4; ++r) {
                    int row = i * 16 + rbase + r;
                    h2_s[row * H2S + col] = (bf16_t)fmaxf(acc[i][j][r] + bv, 0.f);
                }
            }
        }
    }
    __syncthreads();

    int crow[4][4];
#pragma unroll
    for (int i = 0; i < 4; ++i)
#pragma unroll
        for (int r = 0; r < 4; ++r) {
            int lr = i * 16 + rbase + r;
            crow[i][r] = perm ? rank[e0 + lr] : (int)blockIdx.x * 64 + lr;
        }

#pragma unroll 1
    for (int nt = 0; nt < 4; ++nt) {
        const int c0 = nt * 256 + w * 64;
        f32x4 acc[4][4];
#pragma unroll
        for (int i = 0; i < 4; ++i)
#pragma unroll
            for (int j = 0; j < 4; ++j) acc[i][j] = f32x4{0.f, 0.f, 0.f, 0.f};
        bf16x8 bcur[4], bnxt[4];
#pragma unroll
        for (int j = 0; j < 4; ++j)
            bcur[j] = *(const bf16x8*)&k3t[(size_t)(c0 + j * 16 + nr16) * 256 + koff];
#pragma unroll 1
        for (int ks = 0; ks < 8; ++ks) {
            const int k0 = ks * 32;
            if (ks < 7) {
#pragma unroll
                for (int j = 0; j < 4; ++j)
                    bnxt[j] = *(const bf16x8*)&k3t[(size_t)(c0 + j * 16 + nr16) * 256 + k0 + 32 + koff];
            }
            bf16x8 af[4];
#pragma unroll
            for (int i = 0; i < 4; ++i)
                af[i] = *(const bf16x8*)&h2_s[(nr16 + i * 16) * H2S + k0 + koff];
#pragma unroll
            for (int i = 0; i < 4; ++i)
#pragma unroll
                for (int j = 0; j < 4; ++j)
                    acc[i][j] = __builtin_amdgcn_mfma_f32_16x16x32_bf16(af[i], bcur[j], acc[i][j], 0, 0, 0);
#pragma unroll
            for (int j = 0; j < 4; ++j) bcur[j] = bnxt[j];
        }
#pragma unroll
        for (int i = 0; i < 4; ++i) {
#pragma unroll
            for (int r = 0; r < 4; ++r) {
                long cr = crow[i][r];
#pragma unroll
                for (int j = 0; j < 4; ++j) {
                    int col = c0 + j * 16 + nr16;
                    we[cr * 1024 + col] = (bf16_t)(acc[i][j][r] + k3bp[col]);
                }
            }
        }
    }
}

// ---- CSR layer: 4-stream gather (4 independent edges per iteration) --------
__global__ __launch_bounds__(256) void gather_stream(const float* __restrict__ h,
                                                     const bf16_t* __restrict__ wt,
                                                     const int* __restrict__ src_s,
                                                     const int* __restrict__ row_off,
                                                     const float* __restrict__ rw,
                                                     const float* __restrict__ cb,
                                                     float* __restrict__ hout,
                                                     int relu, int rev) {
    __shared__ float rws[1024];
    for (int i = threadIdx.x; i < 1024; i += 256) rws[i] = rw[i];
    __syncthreads();
    const int wv = threadIdx.x >> 6, lane = threadIdx.x & 63;
    const int nb = rev ? ((int)gridDim.x - 1 - blockIdx.x) : blockIdx.x;
    const int n = nb * 4 + wv;
    if (n >= NN) return;
    const int o = lane >> 1, half = lane & 1;

    const int b0 = row_off[n], b1 = row_off[n + 1];
    float acc0 = 0.f, acc1 = 0.f, acc2 = 0.f, acc3 = 0.f;
    int k = b0;
    for (; k + 3 < b1; k += 4) {
        int s0 = src_s[k], s1 = src_s[k + 1], s2 = src_s[k + 2], s3 = src_s[k + 3];
        const float4* hA = (const float4*)(h + (size_t)s0 * 32 + half * 16);
        const float4* hB = (const float4*)(h + (size_t)s1 * 32 + half * 16);
        const float4* hC = (const float4*)(h + (size_t)s2 * 32 + half * 16);
        const float4* hD = (const float4*)(h + (size_t)s3 * 32 + half * 16);
        float4 a0 = hA[0], a1 = hA[1], a2 = hA[2], a3 = hA[3];
        float4 b0v = hB[0], b1v = hB[1], b2v = hB[2], b3v = hB[3];
        float4 c0 = hC[0], c1 = hC[1], c2 = hC[2], c3 = hC[3];
        float4 d0 = hD[0], d1 = hD[1], d2 = hD[2], d3 = hD[3];
        const bf16x8* wA = (const bf16x8*)(wt + (size_t)k * 1024 + lane * 16);
        const bf16x8* wB = (const bf16x8*)(wt + (size_t)(k + 1) * 1024 + lane * 16);
        const bf16x8* wC = (const bf16x8*)(wt + (size_t)(k + 2) * 1024 + lane * 16);
        const bf16x8* wD = (const bf16x8*)(wt + (size_t)(k + 3) * 1024 + lane * 16);
        bf16x8 wa0 = wA[0], wa1 = wA[1];
        bf16x8 wb0 = wB[0], wb1 = wB[1];
        bf16x8 wc0 = wC[0], wc1 = wC[1];
        bf16x8 wd0 = wD[0], wd1 = wD[1];
        acc0 += DOT16(a0, a1, a2, a3, wa0, wa1);
        acc1 += DOT16(b0v, b1v, b2v, b3v, wb0, wb1);
        acc2 += DOT16(c0, c1, c2, c3, wc0, wc1);
        acc3 += DOT16(d0, d1, d2, d3, wd0, wd1);
    }
    for (; k < b1; ++k) {
        int s = src_s[k];
        const float4* hp = (const float4*)(h + (size_t)s * 32 + half * 16);
        float4 a0 = hp[0], a1 = hp[1], a2 = hp[2], a3 = hp[3];
        const bf16x8* wp = (const bf16x8*)(wt + (size_t)k * 1024 + lane * 16);
        bf16x8 wa0 = wp[0], wa1 = wp[1];
        acc0 += DOT16(a0, a1, a2, a3, wa0, wa1);
    }
    float acc = (acc0 + acc1) + (acc2 + acc3);

    float rp = 0.f;
    const float4* hn = (const float4*)(h + (size_t)n * 32 + half * 16);
    float4 a = hn[0], b = hn[1], c = hn[2], dd = hn[3];
    const float* rwb = &rws[half * 16 * 32 + o];
    rp += a.x * rwb[0]   + a.y * rwb[32]  + a.z * rwb[64]  + a.w * rwb[96];
    rp += b.x * rwb[128] + b.y * rwb[160] + b.z * rwb[192] + b.w * rwb[224];
    rp += c.x * rwb[256] + c.y * rwb[288] + c.z * rwb[320] + c.w * rwb[352];
    rp += dd.x * rwb[384] + dd.y * rwb[416] + dd.z * rwb[448] + dd.w * rwb[480];

    acc += __shfl_xor(acc, 1, 64);
    rp  += __shfl_xor(rp, 1, 64);
    if (half == 0) {
        float den = fmaxf((float)(b1 - b0), 1.f);
        float v = acc / den + rp + cb[o];
        if (relu) v = fmaxf(v, 0.f);
        hout[(size_t)n * 32 + o] = v;
    }
}

// ---- fallback (ws too small for full w_e): per-edge wave + atomics ---------
__global__ __launch_bounds__(256) void edge_scatter(const float* __restrict__ h,
                                                    const bf16_t* __restrict__ wt,
                                                    const int* __restrict__ src,
                                                    const int* __restrict__ dst,
                                                    float* __restrict__ aggr,
                                                    int e0, int e1) {
    int wv = threadIdx.x >> 6, lane = threadIdx.x & 63;
    int e = e0 + blockIdx.x * 4 + wv;
    if (e >= e1) return;
    int s = src[e], d = dst[e];
    int o = lane & 31, ihalf = lane >> 5;
    const float4* hp = (const float4*)(h + (size_t)s * 32 + ihalf * 16);
    float4 ha = hp[0], hb = hp[1], hcv = hp[2], hd = hp[3];
    const bf16x8* wp = (const bf16x8*)(wt + (size_t)(e - e0) * 1024 + o * 32 + ihalf * 16);
    bf16x8 w0 = wp[0], w1 = wp[1];
    float acc = DOT16(ha, hb, hcv, hd, w0, w1);
    acc += __shfl_xor(acc, 32, 64);
    if (ihalf == 0) atomicAdd(&aggr[(size_t)d * 32 + o], acc);
}

__global__ __launch_bounds__(256) void node_update(const float* __restrict__ hin,
                                                   const float* __restrict__ aggr,
                                                   const int* __restrict__ cnti,
                                                   const float* __restrict__ rw,
                                                   const float* __restrict__ cb,
                                                   float* __restrict__ hout, int relu) {
    __shared__ float rws[32 * 32];
    for (int i = threadIdx.x; i < 1024; i += 256) rws[i] = rw[i];
    __syncthreads();
    int gid = blockIdx.x * 256 + threadIdx.x;
    int n = gid >> 5, o = gid & 31;
    float den = fmaxf((float)cnti[n], 1.f);
    float acc = aggr[gid] / den + cb[o];
    const float* hrow = hin + (size_t)n * 32;
#pragma unroll
    for (int j = 0; j < 32; ++j) acc += hrow[j] * rws[j * 32 + o];
    if (relu) acc = fmaxf(acc, 0.f);
    hout[gid] = acc;
}

// out = relu(h @ fc2 + b2) @ fc3 + b3
__global__ __launch_bounds__(256) void head_kernel(const float* __restrict__ h,
                                                   const float* __restrict__ w2,
                                                   const float* __restrict__ b2,
                                                   const float* __restrict__ w3,
                                                   const float* __restrict__ b3,
                                                   void* __restrict__ out,
                                                   const int* __restrict__ isf32) {
    int wave = threadIdx.x >> 6, lane = threadIdx.x & 63;
    int n = blockIdx.x * 4 + wave;
    if (n >= NN) return;
    const float* hrow = h + (size_t)n * 32;
    float hr[32];
#pragma unroll
    for (int j = 0; j < 32; ++j) hr[j] = hrow[j];
    int o0 = lane * 2, o1 = lane * 2 + 1;
    float v0 = b2[o0], v1 = b2[o1];
#pragma unroll
    for (int j = 0; j < 32; ++j) {
        float hj = hr[j];
        v0 += hj * w2[j * 128 + o0];
        v1 += hj * w2[j * 128 + o1];
    }
    float y = fmaxf(v0, 0.f) * w3[o0] + fmaxf(v1, 0.f) * w3[o1];
#pragma unroll
    for (int m = 1; m < 64; m <<= 1) y += __shfl_xor(y, m, 64);
    if (lane == 0) {
        float r = y + b3[0];
        if (*isf32) ((float*)out)[n] = r;
        else        ((bf16_t*)out)[n] = (bf16_t)r;
    }
}

// ---------------------------------------------------------------------------

extern "C" void kernel_launch(void* const* d_in, const int* in_sizes, int n_in,
                              void* d_out, int out_size, void* d_ws, size_t ws_size,
                              hipStream_t stream) {
    const int* ei = (const int*)d_in[1];

    char* ws = (char*)d_ws;
    size_t off = 0;
    auto alignup = [](size_t b) { return (b + 255) & ~(size_t)255; };
    auto alloc = [&](size_t bytes) {
        char* p = ws + off;
        off += alignup(bytes);
        return (void*)p;
    };
    float*  h_a   = (float*)alloc((size_t)NN * 32 * 4);
    float*  h_b   = (float*)alloc((size_t)NN * 32 * 4);
    char*   zbase = ws + off;
    int*    cnti  = (int*)alloc((size_t)NN * 4);
    int*    f32fl = (int*)alloc(256);
    int*    idxfl = (int*)alloc(256);
    size_t  zlen  = (ws + off) - zbase;
    int*    rowo  = (int*)alloc((size_t)(NN + 1) * 4);
    int*    pos   = (int*)alloc((size_t)NN * 4);
    int*    srcb  = (int*)alloc((size_t)EE * 4);
    int*    dstb  = (int*)alloc((size_t)EE * 4);
    int*    rankb = (int*)alloc((size_t)E_PAD * 4);
    int*    src_s = (int*)alloc((size_t)E_PAD * 4);
    bf16_t* k2t   = (bf16_t*)alloc(256 * 128 * 2);
    bf16_t* k3t   = (bf16_t*)alloc(1024 * 256 * 2);
    float*  k3bp  = (float*)alloc(1024 * 4);

    static const int fidx[N_FLT] = {0, 2, 3, 4, 5, 6, 7, 8, 9, 10, 11, 12, 13, 14, 15, 16};
    static const int fn[N_FLT]   = {NN * 6, EE * 6, 192, 32, 768, 128, 32768, 256,
                                    262144, 1024, 1024, 32, 4096, 128, 128, 1};
    int foffs[N_FLT];
    int tot = 0;
    for (int i = 0; i < N_FLT; ++i) { foffs[i] = tot; tot += fn[i]; }
    float* canon = (float*)alloc((size_t)tot * 4);
    const float* c_ea   = canon + foffs[1];
    const float* c_k1w  = canon + foffs[4];
    const float* c_k1b  = canon + foffs[5];
    const float* c_k2b  = canon + foffs[7];
    const float* c_rw   = canon + foffs[10];
    const float* c_cb   = canon + foffs[11];
    const float* c_fc2w = canon + foffs[12];
    const float* c_fc2b = canon + foffs[13];
    const float* c_fc3w = canon + foffs[14];
    const float* c_fc3b = canon + foffs[15];
    size_t fixed_end = off;

    // ---- mode selection (constant per harness -> graph-safe) ----
    const size_t sz_we = (size_t)E_PAD * 1024 * 2;   // 246 MB
    int mode, T;
    if (ws_size >= fixed_end + sz_we + 1024) { mode = 1; T = NT64; }
    else {
        mode = 0;
        size_t per_tile = (size_t)64 * 1024 * 2;
        size_t extra = alignup((size_t)NN * 32 * 4);
        size_t avail = ws_size > fixed_end + extra + 4096
                     ? ws_size - fixed_end - extra - 4096 : per_tile;
        long t = (long)(avail / per_tile);
        if (t > NT64) t = NT64;
        if (t < 1) t = 1;
        T = (int)t;
    }
    bf16_t* w_e = nullptr;
    float* aggr = nullptr;
    if (mode == 1) {
        w_e = (bf16_t*)alloc(sz_we);
    } else {
        aggr = (float*)alloc((size_t)NN * 32 * 4);
        w_e  = (bf16_t*)alloc((size_t)T * 64 * 1024 * 2);
    }

    hipMemsetAsync(zbase, 0, zlen, stream);

    detect_all<<<32, 256, 0, stream>>>((const unsigned short*)d_in[2], ei, f32fl, idxfl);

    CvtArgs ca;
    for (int i = 0; i < N_FLT; ++i) {
        ca.src[i] = d_in[fidx[i]];
        ca.offs[i] = foffs[i];
        ca.n[i] = fn[i];
    }
    ca.dst = canon;
    ca.tot = tot;
    cvt_misc<<<(tot + MISC_TOT + 255) / 256, 256, 0, stream>>>(ca, f32fl, k2t, k3t,
                                                               k3bp, h_a);

    repack_idx<<<(EE + 255) / 256, 256, 0, stream>>>(ei, idxfl, srcb, dstb, cnti);
    scan_kernel<<<1, 256, 0, stream>>>(cnti, rowo, pos);
    scatter_rank<<<(E_PAD + 255) / 256, 256, 0, stream>>>(dstb, srcb, pos, rankb, src_s);

    float* hc = h_a;
    float* hn = h_b;
    if (mode == 1) {
        fused_prep<<<NT64, 256, 0, stream>>>(c_ea, c_k1w, c_k1b, k2t, c_k2b,
                                             k3t, k3bp, w_e, rankb, 0, 1);
        for (int d = 0; d < 4; ++d) {
            gather_stream<<<(NN + 3) / 4, 256, 0, stream>>>(hc, w_e, src_s, rowo,
                                                            c_rw, c_cb, hn,
                                                            (d < 3) ? 1 : 0, d & 1);
            float* tmp = hc; hc = hn; hn = tmp;
        }
    } else {
        for (int d = 0; d < 4; ++d) {
            hipMemsetAsync(aggr, 0, (size_t)NN * 32 * 4, stream);
            for (int t0 = 0; t0 < NT64; t0 += T) {
                int tl = (t0 + T <= NT64) ? T : (NT64 - t0);
                fused_prep<<<tl, 256, 0, stream>>>(c_ea, c_k1w, c_k1b, k2t, c_k2b,
                                                   k3t, k3bp, w_e, rankb, t0, 0);
                int e0 = t0 * 64;
                int e1 = e0 + tl * 64; if (e1 > EE) e1 = EE;
                if (e1 > e0)
                    edge_scatter<<<(e1 - e0 + 3) / 4, 256, 0, stream>>>(hc, w_e, srcb, dstb,
                                                                        aggr, e0, e1);
            }
            node_update<<<NN * 32 / 256, 256, 0, stream>>>(hc, aggr, cnti, c_rw, c_cb, hn,
                                                           (d < 3) ? 1 : 0);
            float* tmp = hc; hc = hn; hn = tmp;
        }
    }

    head_kernel<<<(NN + 3) / 4, 256, 0, stream>>>(hc, c_fc2w, c_fc2b, c_fc3w, c_fc3b,
                                                  d_out, f32fl);
}

// Round 17
// 487.257 us; speedup vs baseline: 1.0211x; 1.0211x over previous
//
#include <hip/hip_runtime.h>
#include <hip/hip_bf16.h>

#define NN 10000
#define EE 120000
#define E_PAD 120064   // 1876 * 64
#define NT64 1876      // E_PAD / 64

#define H1S 136        // h1 LDS row stride (elems); 68 words ≡ 4 (mod 32)
#define H2S 264        // h2 LDS row stride (elems); 132 words ≡ 4 (mod 32)

typedef __bf16 bf16_t;
typedef __bf16 bf16x8 __attribute__((ext_vector_type(8)));
typedef float f32x4 __attribute__((ext_vector_type(4)));

#define DOT16(A0, A1, A2, A3, W0, W1)                                          \
    (A0.x * (float)W0[0] + A0.y * (float)W0[1] + A0.z * (float)W0[2] +         \
     A0.w * (float)W0[3] + A1.x * (float)W0[4] + A1.y * (float)W0[5] +         \
     A1.z * (float)W0[6] + A1.w * (float)W0[7] + A2.x * (float)W1[0] +         \
     A2.y * (float)W1[1] + A2.z * (float)W1[2] + A2.w * (float)W1[3] +         \
     A3.x * (float)W1[4] + A3.y * (float)W1[5] + A3.z * (float)W1[6] +         \
     A3.w * (float)W1[7])

static __device__ __forceinline__ int clampi(int v) {
    return v < 0 ? 0 : (v >= NN ? NN - 1 : v);
}

// read element i of a raw input tensor per detected dtype, sanitized
static __device__ __forceinline__ float ldf(const void* p, int i, int f) {
    float v = f ? ((const float*)p)[i] : (float)((const bf16_t*)p)[i];
    return isfinite(v) ? v : 0.f;
}

// ---- combined dtype detection (float + index) ------------------------------
__global__ __launch_bounds__(256) void detect_all(const unsigned short* __restrict__ ea_raw,
                                                  const int* __restrict__ ei,
                                                  int* __restrict__ f32fl,
                                                  int* __restrict__ idxfl) {
    int t = blockIdx.x * 256 + threadIdx.x;          // [0, 8192)
    if (ea_raw[t] & 0x8000) atomicOr(f32fl, 1);
    if (t < 4096 && ei[2 * t + 1] != 0) atomicOr(idxfl, 1);
}

// ---- batched convert of all 16 float tensors + fused misc prep -------------
#define N_FLT 16
#define MISC_TOT 615936
struct CvtArgs {
    const void* src[N_FLT];
    float* dst;
    int offs[N_FLT];
    int n[N_FLT];
    int tot;
};

// segments past a.tot: k2 transpose | k3 transpose+permute | k3 bias | h0
__global__ __launch_bounds__(256) void cvt_misc(CvtArgs a, const int* __restrict__ isf32,
                                                bf16_t* __restrict__ k2t,
                                                bf16_t* __restrict__ k3t,
                                                float* __restrict__ k3bp,
                                                float* __restrict__ h0) {
    int i = blockIdx.x * 256 + threadIdx.x;
    int f = *isf32;
    if (i < a.tot) {
        int t = 0;
#pragma unroll
        for (int k = 1; k < N_FLT; ++k) if (i >= a.offs[k]) t = k;
        int il = i - a.offs[t];
        float v;
        if (f) v = ((const float*)a.src[t])[il];
        else   v = (float)((const bf16_t*)a.src[t])[il];
        if (!isfinite(v)) v = 0.f;
        a.dst[i] = v;
        return;
    }
    int j = i - a.tot;
    if (j >= MISC_TOT) return;
    const void* k2w  = a.src[6];
    const void* k3w  = a.src[8];
    const void* k3b  = a.src[9];
    const void* x    = a.src[0];
    const void* fc1w = a.src[2];
    const void* fc1b = a.src[3];
    if (j < 32768) {                       // k2t[n*128+k] = k2w[k*256+n]
        int n = j >> 7, k = j & 127;
        k2t[j] = (bf16_t)ldf(k2w, k * 256 + n, f);
    } else if (j < 294912) {               // k3t[n*256+k] = k3w[k*1024+perm(n)]
        int idx = j - 32768;
        int n = idx >> 8, k = idx & 255;
        int c = ((n & 31) << 5) | (n >> 5);
        k3t[idx] = (bf16_t)ldf(k3w, k * 1024 + c, f);
    } else if (j < 295936) {               // k3bp
        int n = j - 294912;
        k3bp[n] = ldf(k3b, ((n & 31) << 5) | (n >> 5), f);
    } else {                               // h0 = x @ fc1_w + fc1_b
        int gid = j - 295936;
        int n = gid >> 5, o = gid & 31;
        float acc = ldf(fc1b, o, f);
#pragma unroll
        for (int jj = 0; jj < 6; ++jj) acc += ldf(x, n * 6 + jj, f) * ldf(fc1w, jj * 32 + o, f);
        h0[gid] = acc;
    }
}

__global__ __launch_bounds__(256) void repack_idx(const int* __restrict__ ei,
                                                  const int* __restrict__ flag,
                                                  int* __restrict__ s,
                                                  int* __restrict__ d,
                                                  int* __restrict__ cnti) {
    int e = blockIdx.x * 256 + threadIdx.x;
    if (e >= EE) return;
    int sv, dv;
    if (*flag == 0) {   // int64
        sv = clampi(ei[2 * e]);
        dv = clampi(ei[2 * (EE + e)]);
    } else {            // int32
        sv = clampi(ei[e]);
        dv = clampi(ei[EE + e]);
    }
    s[e] = sv;
    d[e] = dv;
    atomicAdd(&cnti[dv], 1);
}

// single-block exclusive scan of cnti[NN] -> row_off[NN+1], pos copy
__global__ __launch_bounds__(256) void scan_kernel(const int* __restrict__ cnti,
                                                   int* __restrict__ row_off,
                                                   int* __restrict__ pos) {
    __shared__ int part[256];
    const int t = threadIdx.x;
    const int CH = (NN + 255) / 256;
    int s = 0;
    for (int i = 0; i < CH; ++i) {
        int idx = t * CH + i;
        if (idx < NN) s += cnti[idx];
    }
    part[t] = s;
    __syncthreads();
    for (int off = 1; off < 256; off <<= 1) {
        int tmp = (t >= off) ? part[t - off] : 0;
        __syncthreads();
        part[t] += tmp;
        __syncthreads();
    }
    int run = part[t] - s;
    for (int i = 0; i < CH; ++i) {
        int idx = t * CH + i;
        if (idx < NN) {
            row_off[idx] = run;
            pos[idx] = run;
            run += cnti[idx];
        }
    }
    if (t == 255) row_off[NN] = run;
}

// rank[e] = dst-sorted position of edge e; src_s[p] = src of sorted edge p
__global__ __launch_bounds__(256) void scatter_rank(const int* __restrict__ dst,
                                                    const int* __restrict__ src,
                                                    int* __restrict__ pos,
                                                    int* __restrict__ rank,
                                                    int* __restrict__ src_s) {
    int e = blockIdx.x * 256 + threadIdx.x;
    if (e >= E_PAD) return;
    if (e >= EE) { rank[e] = e; return; }
    int p = atomicAdd(&pos[dst[e]], 1);
    rank[e] = p;
    src_s[p] = src[e];
}

// ---- FUSED PREP v3 (round-11 exact; measured 174 us, FETCH ~8 MB) ----------
__global__ __launch_bounds__(256, 3) void fused_prep(const float* __restrict__ ea,
                                                     const float* __restrict__ k1w,
                                                     const float* __restrict__ k1b,
                                                     const bf16_t* __restrict__ k2t,
                                                     const float* __restrict__ k2b,
                                                     const bf16_t* __restrict__ k3t,
                                                     const float* __restrict__ k3bp,
                                                     bf16_t* __restrict__ we,
                                                     const int* __restrict__ rank,
                                                     int tile0, int perm) {
    __shared__ bf16_t h1_s[64 * H1S];   // 17408 B
    __shared__ bf16_t h2_s[64 * H2S];   // 33792 B
    float* ea_s  = (float*)h2_s;
    float* k1w_s = ea_s + 384;
    float* k1b_s = k1w_s + 768;

    const int t = threadIdx.x;
    const int e0 = (tile0 + blockIdx.x) * 64;

    for (int i = t; i < 384; i += 256) {
        int r = i / 6, j = i - r * 6;
        int e = e0 + r;
        ea_s[i] = (e < EE) ? ea[(size_t)e * 6 + j] : 0.f;
    }
    for (int i = t; i < 768; i += 256) k1w_s[i] = k1w[i];
    if (t < 128) k1b_s[t] = k1b[t];
    __syncthreads();

    {
        const int o = t & 127, rh = t >> 7;
        for (int r = rh * 32; r < rh * 32 + 32; ++r) {
            float acc = k1b_s[o];
#pragma unroll
            for (int j = 0; j < 6; ++j) acc += ea_s[r * 6 + j] * k1w_s[j * 128 + o];
            h1_s[r * H1S + o] = (bf16_t)fmaxf(acc, 0.f);
        }
    }
    __syncthreads();

    const int lane = t & 63;
    const int w = t >> 6;
    const int nr16 = lane & 15;
    const int koff = (lane >> 4) * 8;
    const int rbase = (lane >> 4) * 4;

    {
        f32x4 acc[4][4];
#pragma unroll
        for (int i = 0; i < 4; ++i)
#pragma unroll
            for (int j = 0; j < 4; ++j) acc[i][j] = f32x4{0.f, 0.f, 0.f, 0.f};
        bf16x8 bcur[4], bnxt[4];
#pragma unroll
        for (int j = 0; j < 4; ++j)
            bcur[j] = *(const bf16x8*)&k2t[(w * 64 + j * 16 + nr16) * 128 + koff];
#pragma unroll 1
        for (int ks = 0; ks < 4; ++ks) {
            const int k0 = ks * 32;
            if (ks < 3) {
#pragma unroll
                for (int j = 0; j < 4; ++j)
                    bnxt[j] = *(const bf16x8*)&k2t[(w * 64 + j * 16 + nr16) * 128 + k0 + 32 + koff];
            }
            bf16x8 af[4];
#pragma unroll
            for (int i = 0; i < 4; ++i)
                af[i] = *(const bf16x8*)&h1_s[(nr16 + i * 16) * H1S + k0 + koff];
#pragma unroll
            for (int i = 0; i < 4; ++i)
#pragma unroll
                for (int j = 0; j < 4; ++j)
                    acc[i][j] = __builtin_amdgcn_mfma_f32_16x16x32_bf16(af[i], bcur[j], acc[i][j], 0, 0, 0);
#pragma unroll
            for (int j = 0; j < 4; ++j) bcur[j] = bnxt[j];
        }
#pragma unroll
        for (int i = 0; i < 4; ++i) {
#pragma unroll
            for (int j = 0; j < 4; ++j) {
                int col = w * 64 + j * 16 + nr16;
                float bv = k2b[col];
#pragma unroll
                for (int r = 0; r < 4; ++r) {
                    int row = i * 16 + rbase + r;
                    h2_s[row * H2S + col] = (bf16_t)fmaxf(acc[i][j][r] + bv, 0.f);
                }
            }
        }
    }
    __syncthreads();

    int crow[4][4];
#pragma unroll
    for (int i = 0; i < 4; ++i)
#pragma unroll
        for (int r = 0; r < 4; ++r) {
            int lr = i * 16 + rbase + r;
            crow[i][r] = perm ? rank[e0 + lr] : (int)blockIdx.x * 64 + lr;
        }

#pragma unroll 1
    for (int nt = 0; nt < 4; ++nt) {
        const int c0 = nt * 256 + w * 64;
        f32x4 acc[4][4];
#pragma unroll
        for (int i = 0; i < 4; ++i)
#pragma unroll
            for (int j = 0; j < 4; ++j) acc[i][j] = f32x4{0.f, 0.f, 0.f, 0.f};
        bf16x8 bcur[4], bnxt[4];
#pragma unroll
        for (int j = 0; j < 4; ++j)
            bcur[j] = *(const bf16x8*)&k3t[(size_t)(c0 + j * 16 + nr16) * 256 + koff];
#pragma unroll 1
        for (int ks = 0; ks < 8; ++ks) {
            const int k0 = ks * 32;
            if (ks < 7) {
#pragma unroll
                for (int j = 0; j < 4; ++j)
                    bnxt[j] = *(const bf16x8*)&k3t[(size_t)(c0 + j * 16 + nr16) * 256 + k0 + 32 + koff];
            }
            bf16x8 af[4];
#pragma unroll
            for (int i = 0; i < 4; ++i)
                af[i] = *(const bf16x8*)&h2_s[(nr16 + i * 16) * H2S + k0 + koff];
#pragma unroll
            for (int i = 0; i < 4; ++i)
#pragma unroll
                for (int j = 0; j < 4; ++j)
                    acc[i][j] = __builtin_amdgcn_mfma_f32_16x16x32_bf16(af[i], bcur[j], acc[i][j], 0, 0, 0);
#pragma unroll
            for (int j = 0; j < 4; ++j) bcur[j] = bnxt[j];
        }
#pragma unroll
        for (int i = 0; i < 4; ++i) {
#pragma unroll
            for (int r = 0; r < 4; ++r) {
                long cr = crow[i][r];
#pragma unroll
                for (int j = 0; j < 4; ++j) {
                    int col = c0 + j * 16 + nr16;
                    we[cr * 1024 + col] = (bf16_t)(acc[i][j][r] + k3bp[col]);
                }
            }
        }
    }
}

// ---- CSR layer: 2-stream pipelined gather (round-15 exact; best measured) --
__global__ __launch_bounds__(256) void gather_stream(const float* __restrict__ h,
                                                     const bf16_t* __restrict__ wt,
                                                     const int* __restrict__ src_s,
                                                     const int* __restrict__ row_off,
                                                     const float* __restrict__ rw,
                                                     const float* __restrict__ cb,
                                                     float* __restrict__ hout,
                                                     int relu, int rev) {
    __shared__ float rws[1024];
    for (int i = threadIdx.x; i < 1024; i += 256) rws[i] = rw[i];
    __syncthreads();
    const int wv = threadIdx.x >> 6, lane = threadIdx.x & 63;
    const int nb = rev ? ((int)gridDim.x - 1 - blockIdx.x) : blockIdx.x;
    const int n = nb * 4 + wv;
    if (n >= NN) return;
    const int o = lane >> 1, half = lane & 1;

    const int b0 = row_off[n], b1 = row_off[n + 1];
    float acc0 = 0.f, acc1 = 0.f;
    int k = b0;
    if (b1 - b0 >= 2) {
        int sA = src_s[k], sB = src_s[k + 1];
        const float4* hA = (const float4*)(h + (size_t)sA * 32 + half * 16);
        const float4* hB = (const float4*)(h + (size_t)sB * 32 + half * 16);
        float4 ha0 = hA[0], ha1 = hA[1], ha2 = hA[2], ha3 = hA[3];
        float4 hb0 = hB[0], hb1 = hB[1], hb2 = hB[2], hb3 = hB[3];
        const bf16x8* wA = (const bf16x8*)(wt + (size_t)k * 1024 + lane * 16);
        const bf16x8* wB = (const bf16x8*)(wt + (size_t)(k + 1) * 1024 + lane * 16);
        bf16x8 wa0 = wA[0], wa1 = wA[1];
        bf16x8 wb0 = wB[0], wb1 = wB[1];
        while (k + 3 < b1) {
            int sC = src_s[k + 2], sD = src_s[k + 3];
            const float4* hC = (const float4*)(h + (size_t)sC * 32 + half * 16);
            const float4* hD = (const float4*)(h + (size_t)sD * 32 + half * 16);
            float4 hc0 = hC[0], hc1 = hC[1], hc2 = hC[2], hc3 = hC[3];
            float4 hd0 = hD[0], hd1 = hD[1], hd2 = hD[2], hd3 = hD[3];
            const bf16x8* wC = (const bf16x8*)(wt + (size_t)(k + 2) * 1024 + lane * 16);
            const bf16x8* wD = (const bf16x8*)(wt + (size_t)(k + 3) * 1024 + lane * 16);
            bf16x8 wc0 = wC[0], wc1 = wC[1];
            bf16x8 wd0 = wD[0], wd1 = wD[1];
            acc0 += DOT16(ha0, ha1, ha2, ha3, wa0, wa1);
            acc1 += DOT16(hb0, hb1, hb2, hb3, wb0, wb1);
            ha0 = hc0; ha1 = hc1; ha2 = hc2; ha3 = hc3;
            hb0 = hd0; hb1 = hd1; hb2 = hd2; hb3 = hd3;
            wa0 = wc0; wa1 = wc1; wb0 = wd0; wb1 = wd1;
            k += 2;
        }
        acc0 += DOT16(ha0, ha1, ha2, ha3, wa0, wa1);
        acc1 += DOT16(hb0, hb1, hb2, hb3, wb0, wb1);
        k += 2;
    }
    for (; k < b1; ++k) {
        int s = src_s[k];
        const float4* hp = (const float4*)(h + (size_t)s * 32 + half * 16);
        float4 ha0 = hp[0], ha1 = hp[1], ha2 = hp[2], ha3 = hp[3];
        const bf16x8* wp = (const bf16x8*)(wt + (size_t)k * 1024 + lane * 16);
        bf16x8 wa0 = wp[0], wa1 = wp[1];
        acc0 += DOT16(ha0, ha1, ha2, ha3, wa0, wa1);
    }
    float acc = acc0 + acc1;

    float rp = 0.f;
    const float4* hn = (const float4*)(h + (size_t)n * 32 + half * 16);
    float4 a = hn[0], b = hn[1], c = hn[2], dd = hn[3];
    const float* rwb = &rws[half * 16 * 32 + o];
    rp += a.x * rwb[0]   + a.y * rwb[32]  + a.z * rwb[64]  + a.w * rwb[96];
    rp += b.x * rwb[128] + b.y * rwb[160] + b.z * rwb[192] + b.w * rwb[224];
    rp += c.x * rwb[256] + c.y * rwb[288] + c.z * rwb[320] + c.w * rwb[352];
    rp += dd.x * rwb[384] + dd.y * rwb[416] + dd.z * rwb[448] + dd.w * rwb[480];

    acc += __shfl_xor(acc, 1, 64);
    rp  += __shfl_xor(rp, 1, 64);
    if (half == 0) {
        float den = fmaxf((float)(b1 - b0), 1.f);
        float v = acc / den + rp + cb[o];
        if (relu) v = fmaxf(v, 0.f);
        hout[(size_t)n * 32 + o] = v;
    }
}

// ---- fallback (ws too small for full w_e): per-edge wave + atomics ---------
__global__ __launch_bounds__(256) void edge_scatter(const float* __restrict__ h,
                                                    const bf16_t* __restrict__ wt,
                                                    const int* __restrict__ src,
                                                    const int* __restrict__ dst,
                                                    float* __restrict__ aggr,
                                                    int e0, int e1) {
    int wv = threadIdx.x >> 6, lane = threadIdx.x & 63;
    int e = e0 + blockIdx.x * 4 + wv;
    if (e >= e1) return;
    int s = src[e], d = dst[e];
    int o = lane & 31, ihalf = lane >> 5;
    const float4* hp = (const float4*)(h + (size_t)s * 32 + ihalf * 16);
    float4 ha = hp[0], hb = hp[1], hcv = hp[2], hd = hp[3];
    const bf16x8* wp = (const bf16x8*)(wt + (size_t)(e - e0) * 1024 + o * 32 + ihalf * 16);
    bf16x8 w0 = wp[0], w1 = wp[1];
    float acc = DOT16(ha, hb, hcv, hd, w0, w1);
    acc += __shfl_xor(acc, 32, 64);
    if (ihalf == 0) atomicAdd(&aggr[(size_t)d * 32 + o], acc);
}

__global__ __launch_bounds__(256) void node_update(const float* __restrict__ hin,
                                                   const float* __restrict__ aggr,
                                                   const int* __restrict__ cnti,
                                                   const float* __restrict__ rw,
                                                   const float* __restrict__ cb,
                                                   float* __restrict__ hout, int relu) {
    __shared__ float rws[32 * 32];
    for (int i = threadIdx.x; i < 1024; i += 256) rws[i] = rw[i];
    __syncthreads();
    int gid = blockIdx.x * 256 + threadIdx.x;
    int n = gid >> 5, o = gid & 31;
    float den = fmaxf((float)cnti[n], 1.f);
    float acc = aggr[gid] / den + cb[o];
    const float* hrow = hin + (size_t)n * 32;
#pragma unroll
    for (int j = 0; j < 32; ++j) acc += hrow[j] * rws[j * 32 + o];
    if (relu) acc = fmaxf(acc, 0.f);
    hout[gid] = acc;
}

// out = relu(h @ fc2 + b2) @ fc3 + b3
__global__ __launch_bounds__(256) void head_kernel(const float* __restrict__ h,
                                                   const float* __restrict__ w2,
                                                   const float* __restrict__ b2,
                                                   const float* __restrict__ w3,
                                                   const float* __restrict__ b3,
                                                   void* __restrict__ out,
                                                   const int* __restrict__ isf32) {
    int wave = threadIdx.x >> 6, lane = threadIdx.x & 63;
    int n = blockIdx.x * 4 + wave;
    if (n >= NN) return;
    const float* hrow = h + (size_t)n * 32;
    float hr[32];
#pragma unroll
    for (int j = 0; j < 32; ++j) hr[j] = hrow[j];
    int o0 = lane * 2, o1 = lane * 2 + 1;
    float v0 = b2[o0], v1 = b2[o1];
#pragma unroll
    for (int j = 0; j < 32; ++j) {
        float hj = hr[j];
        v0 += hj * w2[j * 128 + o0];
        v1 += hj * w2[j * 128 + o1];
    }
    float y = fmaxf(v0, 0.f) * w3[o0] + fmaxf(v1, 0.f) * w3[o1];
#pragma unroll
    for (int m = 1; m < 64; m <<= 1) y += __shfl_xor(y, m, 64);
    if (lane == 0) {
        float r = y + b3[0];
        if (*isf32) ((float*)out)[n] = r;
        else        ((bf16_t*)out)[n] = (bf16_t)r;
    }
}

// ---------------------------------------------------------------------------

extern "C" void kernel_launch(void* const* d_in, const int* in_sizes, int n_in,
                              void* d_out, int out_size, void* d_ws, size_t ws_size,
                              hipStream_t stream) {
    const int* ei = (const int*)d_in[1];

    char* ws = (char*)d_ws;
    size_t off = 0;
    auto alignup = [](size_t b) { return (b + 255) & ~(size_t)255; };
    auto alloc = [&](size_t bytes) {
        char* p = ws + off;
        off += alignup(bytes);
        return (void*)p;
    };
    float*  h_a   = (float*)alloc((size_t)NN * 32 * 4);
    float*  h_b   = (float*)alloc((size_t)NN * 32 * 4);
    char*   zbase = ws + off;
    int*    cnti  = (int*)alloc((size_t)NN * 4);
    int*    f32fl = (int*)alloc(256);
    int*    idxfl = (int*)alloc(256);
    size_t  zlen  = (ws + off) - zbase;
    int*    rowo  = (int*)alloc((size_t)(NN + 1) * 4);
    int*    pos   = (int*)alloc((size_t)NN * 4);
    int*    srcb  = (int*)alloc((size_t)EE * 4);
    int*    dstb  = (int*)alloc((size_t)EE * 4);
    int*    rankb = (int*)alloc((size_t)E_PAD * 4);
    int*    src_s = (int*)alloc((size_t)E_PAD * 4);
    bf16_t* k2t   = (bf16_t*)alloc(256 * 128 * 2);
    bf16_t* k3t   = (bf16_t*)alloc(1024 * 256 * 2);
    float*  k3bp  = (float*)alloc(1024 * 4);

    static const int fidx[N_FLT] = {0, 2, 3, 4, 5, 6, 7, 8, 9, 10, 11, 12, 13, 14, 15, 16};
    static const int fn[N_FLT]   = {NN * 6, EE * 6, 192, 32, 768, 128, 32768, 256,
                                    262144, 1024, 1024, 32, 4096, 128, 128, 1};
    int foffs[N_FLT];
    int tot = 0;
    for (int i = 0; i < N_FLT; ++i) { foffs[i] = tot; tot += fn[i]; }
    float* canon = (float*)alloc((size_t)tot * 4);
    const float* c_ea   = canon + foffs[1];
    const float* c_k1w  = canon + foffs[4];
    const float* c_k1b  = canon + foffs[5];
    const float* c_k2b  = canon + foffs[7];
    const float* c_rw   = canon + foffs[10];
    const float* c_cb   = canon + foffs[11];
    const float* c_fc2w = canon + foffs[12];
    const float* c_fc2b = canon + foffs[13];
    const float* c_fc3w = canon + foffs[14];
    const float* c_fc3b = canon + foffs[15];
    size_t fixed_end = off;

    // ---- mode selection (constant per harness -> graph-safe) ----
    const size_t sz_we = (size_t)E_PAD * 1024 * 2;   // 246 MB
    int mode, T;
    if (ws_size >= fixed_end + sz_we + 1024) { mode = 1; T = NT64; }
    else {
        mode = 0;
        size_t per_tile = (size_t)64 * 1024 * 2;
        size_t extra = alignup((size_t)NN * 32 * 4);
        size_t avail = ws_size > fixed_end + extra + 4096
                     ? ws_size - fixed_end - extra - 4096 : per_tile;
        long t = (long)(avail / per_tile);
        if (t > NT64) t = NT64;
        if (t < 1) t = 1;
        T = (int)t;
    }
    bf16_t* w_e = nullptr;
    float* aggr = nullptr;
    if (mode == 1) {
        w_e = (bf16_t*)alloc(sz_we);
    } else {
        aggr = (float*)alloc((size_t)NN * 32 * 4);
        w_e  = (bf16_t*)alloc((size_t)T * 64 * 1024 * 2);
    }

    hipMemsetAsync(zbase, 0, zlen, stream);

    detect_all<<<32, 256, 0, stream>>>((const unsigned short*)d_in[2], ei, f32fl, idxfl);

    CvtArgs ca;
    for (int i = 0; i < N_FLT; ++i) {
        ca.src[i] = d_in[fidx[i]];
        ca.offs[i] = foffs[i];
        ca.n[i] = fn[i];
    }
    ca.dst = canon;
    ca.tot = tot;
    cvt_misc<<<(tot + MISC_TOT + 255) / 256, 256, 0, stream>>>(ca, f32fl, k2t, k3t,
                                                               k3bp, h_a);

    repack_idx<<<(EE + 255) / 256, 256, 0, stream>>>(ei, idxfl, srcb, dstb, cnti);
    scan_kernel<<<1, 256, 0, stream>>>(cnti, rowo, pos);
    scatter_rank<<<(E_PAD + 255) / 256, 256, 0, stream>>>(dstb, srcb, pos, rankb, src_s);

    float* hc = h_a;
    float* hn = h_b;
    if (mode == 1) {
        fused_prep<<<NT64, 256, 0, stream>>>(c_ea, c_k1w, c_k1b, k2t, c_k2b,
                                             k3t, k3bp, w_e, rankb, 0, 1);
        for (int d = 0; d < 4; ++d) {
            gather_stream<<<(NN + 3) / 4, 256, 0, stream>>>(hc, w_e, src_s, rowo,
                                                            c_rw, c_cb, hn,
                                                            (d < 3) ? 1 : 0, d & 1);
            float* tmp = hc; hc = hn; hn = tmp;
        }
    } else {
        for (int d = 0; d < 4; ++d) {
            hipMemsetAsync(aggr, 0, (size_t)NN * 32 * 4, stream);
            for (int t0 = 0; t0 < NT64; t0 += T) {
                int tl = (t0 + T <= NT64) ? T : (NT64 - t0);
                fused_prep<<<tl, 256, 0, stream>>>(c_ea, c_k1w, c_k1b, k2t, c_k2b,
                                                   k3t, k3bp, w_e, rankb, t0, 0);
                int e0 = t0 * 64;
                int e1 = e0 + tl * 64; if (e1 > EE) e1 = EE;
                if (e1 > e0)
                    edge_scatter<<<(e1 - e0 + 3) / 4, 256, 0, stream>>>(hc, w_e, srcb, dstb,
                                                                        aggr, e0, e1);
            }
            node_update<<<NN * 32 / 256, 256, 0, stream>>>(hc, aggr, cnti, c_rw, c_cb, hn,
                                                           (d < 3) ? 1 : 0);
            float* tmp = hc; hc = hn; hn = tmp;
        }
    }

    head_kernel<<<(NN + 3) / 4, 256, 0, stream>>>(hc, c_fc2w, c_fc2b, c_fc3w, c_fc3b,
                                                  d_out, f32fl);
}